// Round 7
// baseline (706.850 us; speedup 1.0000x reference)
//
#include <hip/hip_runtime.h>

// Problem constants (fixed by reference)
#define BB 256      // batch
#define TT 1024     // time steps
#define HH 32       // hidden
#define NT 512      // 8 waves
#define CH 64       // emb chunk length (steps)
#define NCH 16      // TT/CH chunks

// Asynchronous dataflow pipeline (no __syncthreads in main loop).
// Stages (one wave each), connected by LDS ring buffers + progress flags:
//   wv6 : y1(t)=relu(W1@e)+ y2(t)=relu(W2@y1)      -> y2s ring (8)
//   wv7 : y3(t)=relu(W3@y2)                        -> y3s ring (8); emb refill; out flush
//   wv3 : gi0(t)=Wih0@y3+b                         -> gib[0] ring (4)
//   wv0 : gh0 + gates -> h0(t)                     -> h0s ring (8)   [recurrence in regs]
//   wv4 : gi1(t)=Wih1@h0+b                         -> gib[1] ring (4)
//   wv1 : gh1 + gates -> h1(t)                     -> h1s ring (8)
//   wv5 : gi2(t)=Wih2@h1+b                         -> gib[2] ring (4)
//   wv2 : gh2 + gates -> h2(t)                     -> obuf ring (32), flushed by wv7
// Sync: progress counters (steps completed) in LDS; acquire loads (consumer,
// cached+batched) / release stores (producer, lane 0). Backpressure: producer
// waits consumer_progress >= t - (depth-1). Bounded-buffer => deadlock-free.

#define F_Y2    0
#define F_Y3    1
#define F_GI0   2   // +l
#define F_GH0   5   // +l
#define F_FLUSH 8
#define F_CHUNK 9

__device__ __forceinline__ float fast_rcp(float x) { return __builtin_amdgcn_rcpf(x); }
__device__ __forceinline__ float sigm(float x)     { return fast_rcp(1.f + __expf(-x)); }
__device__ __forceinline__ float tanh_fast(float x){ float e = __expf(2.f * x); return 1.f - 2.f * fast_rcp(e + 1.f); }
__device__ __forceinline__ float rlane(float v, int k) {
    return __int_as_float(__builtin_amdgcn_readlane(__float_as_int(v), k));
}
__device__ __forceinline__ int wait_ge(int* f, int needed, int cached) {
    if (cached >= needed) return cached;
    int v = __hip_atomic_load(f, __ATOMIC_ACQUIRE, __HIP_MEMORY_SCOPE_WORKGROUP);
    while (v < needed)
        v = __hip_atomic_load(f, __ATOMIC_ACQUIRE, __HIP_MEMORY_SCOPE_WORKGROUP);
    __builtin_amdgcn_sched_barrier(0);
    return v;
}
__device__ __forceinline__ void publish(int* f, int v, int ln) {
    asm volatile("s_waitcnt lgkmcnt(0)" ::: "memory");   // ring data visible first
    if (ln == 0) __hip_atomic_store(f, v, __ATOMIC_RELEASE, __HIP_MEMORY_SCOPE_WORKGROUP);
}

__global__ __launch_bounds__(NT, 1) void rnn_fused(
    const int*   __restrict__ xidx,   // [B,T]
    const float* __restrict__ hid,    // [L,B,H]
    const float* __restrict__ emb,    // [38000,H]
    const float* __restrict__ W1, const float* __restrict__ b1,
    const float* __restrict__ W2, const float* __restrict__ b2,
    const float* __restrict__ W3, const float* __restrict__ b3,
    const float* __restrict__ Wih,    // [L,3H,H]
    const float* __restrict__ Whh,    // [L,3H,H]
    const float* __restrict__ bih,    // [L,3H]
    const float* __restrict__ bhh,    // [L,3H]
    float*       __restrict__ out)    // [B*T*H] ++ [L*B*H]
{
    const int b   = blockIdx.x;
    const int tid = threadIdx.x;
    const int wv  = tid >> 6;
    const int ln  = tid & 63;
    const int lo  = ln & 31;

    __shared__ int idxbuf[TT];                       // 4 KB
    __shared__ alignas(16) float ebuf[4][CH][HH];    // 32 KB emb chunk ring
    __shared__ alignas(16) float y2s[8][HH];
    __shared__ alignas(16) float y3s[8][HH];
    __shared__ alignas(16) float h0s[8][HH];
    __shared__ alignas(16) float h1s[8][HH];
    __shared__ alignas(16) float gib[3][4][96];      // gi results, ring depth 4
    __shared__ alignas(16) float obuf[32][HH];       // layer-2 output ring
    __shared__ int flg[16];

    // ---- preamble (barriers allowed here) ----
    if (tid < 16) flg[tid] = 0;
    for (int t = tid; t < TT; t += NT) idxbuf[t] = xidx[b * TT + t];
    __syncthreads();

    {   // preload emb chunks 0 and 1 (1024 float4 tasks over 512 threads)
        float4*       edst = reinterpret_cast<float4*>(&ebuf[0][0][0]);
        const float4* esrc = reinterpret_cast<const float4*>(emb);
        #pragma unroll
        for (int k = 0; k < 2; ++k) {
            const int task = k * NT + tid, row = task >> 3, q = task & 7;
            edst[row * 8 + q] = esrc[(size_t)idxbuf[row] * 8 + q];
        }
    }

    // ---- per-role weights ----
    float wA[32], wB[32];
    float bA = 0.f, bB = 0.f;
    float v_h = 0.f;

    if (wv < 3) {                       // gh: Whh rows {ln, 64+lo}
        const float4* pA = reinterpret_cast<const float4*>(Whh + (size_t)(wv * 96 + ln) * HH);
        const float4* pB = reinterpret_cast<const float4*>(Whh + (size_t)(wv * 96 + 64 + lo) * HH);
        #pragma unroll
        for (int i = 0; i < 8; ++i) {
            reinterpret_cast<float4*>(wA)[i] = pA[i];
            reinterpret_cast<float4*>(wB)[i] = pB[i];
        }
        bA = bhh[wv * 96 + ln];
        bB = bhh[wv * 96 + 64 + lo];
        if (ln < HH) v_h = hid[(size_t)(wv * BB + b) * HH + ln];
    } else if (wv < 6) {                // gi: Wih rows {ln, 64+lo}
        const int l = wv - 3;
        const float4* pA = reinterpret_cast<const float4*>(Wih + (size_t)(l * 96 + ln) * HH);
        const float4* pB = reinterpret_cast<const float4*>(Wih + (size_t)(l * 96 + 64 + lo) * HH);
        #pragma unroll
        for (int i = 0; i < 8; ++i) {
            reinterpret_cast<float4*>(wA)[i] = pA[i];
            reinterpret_cast<float4*>(wB)[i] = pB[i];
        }
        bA = bih[l * 96 + ln];
        bB = bih[l * 96 + 64 + lo];
    } else if (wv == 6) {               // W1 row lo, W2 row lo
        const float4* p1 = reinterpret_cast<const float4*>(W1 + (size_t)lo * HH);
        const float4* p2 = reinterpret_cast<const float4*>(W2 + (size_t)lo * HH);
        #pragma unroll
        for (int i = 0; i < 8; ++i) {
            reinterpret_cast<float4*>(wA)[i] = p1[i];
            reinterpret_cast<float4*>(wB)[i] = p2[i];
        }
        bA = b1[lo];
        bB = b2[lo];
    } else {                            // wv7: W3 row lo
        const float4* p3 = reinterpret_cast<const float4*>(W3 + (size_t)lo * HH);
        #pragma unroll
        for (int i = 0; i < 8; ++i) reinterpret_cast<float4*>(wA)[i] = p3[i];
        bA = b3[lo];
    }
    if (tid == 0) flg[F_CHUNK] = 2;
    __syncthreads();

    float* const out_seq = out + (size_t)b * TT * HH;
    float* const out_hf  = out + (size_t)BB * TT * HH;

    if (wv < 3) {
        // ================= gh wave, layer wv (recurrence in registers) =========
        int seenA = 0, seenB = 0;
        for (int t = 0; t < TT; ++t) {
            seenA = wait_ge(&flg[F_GI0 + wv], t + 1, seenA);
            if (wv < 2) seenB = wait_ge(&flg[F_GI0 + wv + 1], t - 7,  seenB);
            else        seenB = wait_ge(&flg[F_FLUSH],        t - 31, seenB);
            const float giA = gib[wv][t & 3][ln];
            const float giB = gib[wv][t & 3][64 + lo];
            float a0 = bA, a1 = 0.f, c0 = bB, c1 = 0.f;
            #pragma unroll
            for (int k = 0; k < 32; k += 2) {
                const float h0 = rlane(v_h, k), h1 = rlane(v_h, k + 1);
                a0 = fmaf(wA[k],     h0, a0);
                a1 = fmaf(wA[k + 1], h1, a1);
                c0 = fmaf(wB[k],     h0, c0);
                c1 = fmaf(wB[k + 1], h1, c1);
            }
            const float ghA = a0 + a1;              // r rows (lanes 0-31), z rows (32-63)
            const float ghB = c0 + c1;              // n rows (dup halves)
            const float sA  = giA + ghA;
            const float zp  = __shfl_xor(sA, 32);
            const float r   = sigm(sA);
            const float z   = sigm(zp);
            const float n   = tanh_fast(fmaf(r, ghB, giB));
            const float hn  = fmaf(z, v_h - n, n);
            v_h = hn;
            if (ln < HH) {
                if (wv == 0)      h0s[t & 7][ln]  = hn;
                else if (wv == 1) h1s[t & 7][ln]  = hn;
                else              obuf[t & 31][ln] = hn;
            }
            publish(&flg[F_GH0 + wv], t + 1, ln);
        }
        if (ln < HH) out_hf[(size_t)(wv * BB + b) * HH + ln] = v_h;
    } else if (wv < 6) {
        // ================= gi wave, layer l ====================================
        const int l = wv - 3;
        const int srcFlag = (l == 0) ? F_Y3 : (F_GH0 + l - 1);
        const float* srcbase = (l == 0) ? &y3s[0][0] : (l == 1) ? &h0s[0][0] : &h1s[0][0];
        int seenA = 0, seenB = 0;
        for (int t = 0; t < TT; ++t) {
            seenA = wait_ge(&flg[srcFlag],   t + 1, seenA);
            seenB = wait_ge(&flg[F_GH0 + l], t - 3, seenB);
            const float vx = srcbase[(t & 7) * HH + lo];
            float a0 = bA, a1 = 0.f, c0 = bB, c1 = 0.f;
            #pragma unroll
            for (int k = 0; k < 32; k += 2) {
                const float x0 = rlane(vx, k), x1 = rlane(vx, k + 1);
                a0 = fmaf(wA[k],     x0, a0);
                a1 = fmaf(wA[k + 1], x1, a1);
                c0 = fmaf(wB[k],     x0, c0);
                c1 = fmaf(wB[k + 1], x1, c1);
            }
            gib[l][t & 3][ln] = a0 + a1;
            if (ln < 32) gib[l][t & 3][64 + ln] = c0 + c1;
            publish(&flg[F_GI0 + l], t + 1, ln);
        }
    } else if (wv == 6) {
        // ================= MLP y1+y2 ===========================================
        int seenC = 0, seenB = 0;
        for (int t = 0; t < TT; ++t) {
            if ((t & 63) == 0) seenC = wait_ge(&flg[F_CHUNK], (t >> 6) + 1, seenC);
            seenB = wait_ge(&flg[F_Y3], t - 7, seenB);
            const float ve = ebuf[(t >> 6) & 3][t & 63][lo];
            float a0 = bA, a1 = 0.f;
            #pragma unroll
            for (int k = 0; k < 32; k += 2) {
                a0 = fmaf(wA[k],     rlane(ve, k),     a0);
                a1 = fmaf(wA[k + 1], rlane(ve, k + 1), a1);
            }
            const float y1 = fmaxf(a0 + a1, 0.f);
            float c0 = bB, c1 = 0.f;
            #pragma unroll
            for (int k = 0; k < 32; k += 2) {
                c0 = fmaf(wB[k],     rlane(y1, k),     c0);
                c1 = fmaf(wB[k + 1], rlane(y1, k + 1), c1);
            }
            const float y2 = fmaxf(c0 + c1, 0.f);
            if (ln < HH) y2s[t & 7][ln] = y2;
            publish(&flg[F_Y2], t + 1, ln);
        }
    } else {
        // ================= wv7: y3 + emb refill + output flush ================
        int seenY = 0, seenG = 0, seenGH2 = 0, flushed = 0;
        for (int t = 0; t < TT; ++t) {
            if ((t & 63) == 0) {
                const int cn = (t >> 6) + 2;
                if (cn < NCH) {
                    float4*       edst = reinterpret_cast<float4*>(&ebuf[cn & 3][0][0]);
                    const float4* esrc = reinterpret_cast<const float4*>(emb);
                    const int base = cn * CH;
                    #pragma unroll
                    for (int k = 0; k < 8; ++k) {
                        const int task = k * 64 + ln, row = task >> 3, q = task & 7;
                        edst[row * 8 + q] = esrc[(size_t)idxbuf[base + row] * 8 + q];
                    }
                    publish(&flg[F_CHUNK], cn + 1, ln);
                }
            }
            seenY = wait_ge(&flg[F_Y2],  t + 1, seenY);
            seenG = wait_ge(&flg[F_GI0], t - 7, seenG);
            const float vx = y2s[t & 7][lo];
            float a0 = bA, a1 = 0.f;
            #pragma unroll
            for (int k = 0; k < 32; k += 2) {
                a0 = fmaf(wA[k],     rlane(vx, k),     a0);
                a1 = fmaf(wA[k + 1], rlane(vx, k + 1), a1);
            }
            const float y3 = fmaxf(a0 + a1, 0.f);
            if (ln < HH) y3s[t & 7][ln] = y3;
            publish(&flg[F_Y3], t + 1, ln);
            if ((t & 15) == 15) {
                seenGH2 = __hip_atomic_load(&flg[F_GH0 + 2], __ATOMIC_ACQUIRE, __HIP_MEMORY_SCOPE_WORKGROUP);
                while (seenGH2 >= flushed + 16) {
                    #pragma unroll
                    for (int k = 0; k < 2; ++k) {
                        const int task = k * 64 + ln, row = task >> 3, q = task & 7;
                        const float4 v = *reinterpret_cast<const float4*>(&obuf[(flushed + row) & 31][q * 4]);
                        *reinterpret_cast<float4*>(&out_seq[(size_t)(flushed + row) * HH + q * 4]) = v;
                    }
                    flushed += 16;
                    publish(&flg[F_FLUSH], flushed, ln);
                }
            }
        }
        while (flushed < TT) {          // drain tail
            seenGH2 = wait_ge(&flg[F_GH0 + 2], flushed + 16, seenGH2);
            #pragma unroll
            for (int k = 0; k < 2; ++k) {
                const int task = k * 64 + ln, row = task >> 3, q = task & 7;
                const float4 v = *reinterpret_cast<const float4*>(&obuf[(flushed + row) & 31][q * 4]);
                *reinterpret_cast<float4*>(&out_seq[(size_t)(flushed + row) * HH + q * 4]) = v;
            }
            flushed += 16;
            publish(&flg[F_FLUSH], flushed, ln);
        }
    }
}

extern "C" void kernel_launch(void* const* d_in, const int* in_sizes, int n_in,
                              void* d_out, int out_size, void* d_ws, size_t ws_size,
                              hipStream_t stream) {
    const int*   x   = (const int*)  d_in[0];
    const float* hid = (const float*)d_in[1];
    const float* emb = (const float*)d_in[2];
    const float* W1  = (const float*)d_in[3];
    const float* b1  = (const float*)d_in[4];
    const float* W2  = (const float*)d_in[5];
    const float* b2  = (const float*)d_in[6];
    const float* W3  = (const float*)d_in[7];
    const float* b3  = (const float*)d_in[8];
    const float* Wih = (const float*)d_in[9];
    const float* Whh = (const float*)d_in[10];
    const float* bih = (const float*)d_in[11];
    const float* bhh = (const float*)d_in[12];

    rnn_fused<<<dim3(BB), dim3(NT), 0, stream>>>(
        x, hid, emb, W1, b1, W2, b2, W3, b3, Wih, Whh, bih, bhh, (float*)d_out);
}